// Round 4
// baseline (1002.163 us; speedup 1.0000x reference)
//
#include <hip/hip_runtime.h>

typedef unsigned short ushort_t;
typedef __attribute__((ext_vector_type(4))) unsigned short bfx4;
typedef __attribute__((ext_vector_type(8))) unsigned short bfx8;
typedef __attribute__((ext_vector_type(8))) short sfx8;
typedef __attribute__((ext_vector_type(4))) float fx4;

__device__ __forceinline__ float bf2f(unsigned short u){
  unsigned int x = ((unsigned int)u) << 16;
  float f; __builtin_memcpy(&f, &x, 4); return f;
}
__device__ __forceinline__ unsigned short f2bf(float f){
  unsigned int x; __builtin_memcpy(&x, &f, 4);
  x += 0x7fffu + ((x >> 16) & 1u);
  return (unsigned short)(x >> 16);
}

// ---------------- Kernel A: vdf = v_pre @ W_df^T  -> (N, 12) f32 (9 + 3 pad)
__global__ void k_vdf(const float* __restrict__ vec, const float* __restrict__ wdf,
                      float* __restrict__ vdf, int N)
{
  int n = blockIdx.x * 256 + threadIdx.x;
  if (n >= N) return;
  const fx4* vp = (const fx4*)(vec + (size_t)n * 48);   // vector[n][k][d]
  float v[48];
  #pragma unroll
  for (int t = 0; t < 12; t++){
    fx4 x = vp[t];
    v[t*4+0]=x[0]; v[t*4+1]=x[1]; v[t*4+2]=x[2]; v[t*4+3]=x[3];
  }
  float out[12];
  #pragma unroll
  for (int d = 0; d < 3; d++)
    #pragma unroll
    for (int c = 0; c < 3; c++){
      float a = 0.f;
      #pragma unroll
      for (int k = 0; k < 16; k++) a += v[k*3 + d] * wdf[c*16 + k];  // W_df[c][k] uniform -> s_load
      out[d*3 + c] = a;                                   // vdf[n][d][c]
    }
  out[9] = out[10] = out[11] = 0.f;
  fx4* o4 = (fx4*)(vdf + (size_t)n * 12);
  o4[0] = *(fx4*)(out + 0);
  o4[1] = *(fx4*)(out + 4);
  o4[2] = *(fx4*)(out + 8);
}

// ---------------- Kernel B: edge scatter: sums[row][c*3+i] += F[i][j]*vdf[row][j][c]; cnt++
__global__ void k_edge(const int* __restrict__ ei, const float* __restrict__ frames,
                       const float* __restrict__ vdf, float* __restrict__ sums, int E)
{
  int e = blockIdx.x * 256 + threadIdx.x;
  if (e >= E) return;
  int row = ei[e];
  const fx4* vp = (const fx4*)(vdf + (size_t)row * 12);
  fx4 a = vp[0], b = vp[1], c4 = vp[2];
  float v[9];
  v[0]=a[0]; v[1]=a[1]; v[2]=a[2]; v[3]=a[3];
  v[4]=b[0]; v[5]=b[1]; v[6]=b[2]; v[7]=b[3]; v[8]=c4[0]; // v[j*3+c]
  const float* fp = frames + (size_t)e * 9;               // F[i*3+j], f32
  float F[9];
  #pragma unroll
  for (int t = 0; t < 9; t++) F[t] = fp[t];
  float* sp = sums + (size_t)row * 10;
  #pragma unroll
  for (int c = 0; c < 3; c++)
    #pragma unroll
    for (int i = 0; i < 3; i++){
      float loc = F[i*3+0]*v[0+c] + F[i*3+1]*v[3+c] + F[i*3+2]*v[6+c];
      atomicAdd(&sp[c*3 + i], loc);
    }
  atomicAdd(&sp[9], 1.0f);
}

// ---------------- Kernel C: node main pass (vh, vnorm, merged, MFMA s, silu, gate, vrep)
#define NPB 64
#define MS  168   // padded row stride (elements); 168*2B/4 = 84 ≡ 20 mod 32 -> <=2-way LDS conflicts

__global__ __launch_bounds__(256) void k_node(
    const float* __restrict__ scalar, const float* __restrict__ vec,
    const float* __restrict__ sums,
    const float* __restrict__ wdown, const float* __restrict__ wso,
    const float* __restrict__ bso,   const float* __restrict__ wup,
    const float* __restrict__ wg,    const float* __restrict__ bg,
    float* __restrict__ out0, float* __restrict__ out1, int N)
{
  __shared__ __align__(16) ushort_t sm_merged[NPB * MS];   // merged (bf16); later holds silu(s)
  __shared__ __align__(16) ushort_t sm_wso[128 * MS];      // W_so (bf16, zero-padded K); ALSO f32 staging scratch
  __shared__ __align__(16) ushort_t sm_vh[NPB * 48];       // vh[ni][d][h] bf16
  __shared__ __align__(16) ushort_t sm_wg[16 * 128];       // W_g bf16
  __shared__ float  sm_wup[256];
  __shared__ float  sm_wd[256];
  __shared__ float  sm_bso[128];
  __shared__ float  sm_bg[16];

  const int tid = threadIdx.x;
  const int n0  = blockIdx.x * NPB;

  // ---- P0: zero merged; stage vector tile (f32) into sm_wso scratch; preload W_down
  for (int i = tid; i < NPB*MS/2; i += 256) ((unsigned int*)sm_merged)[i] = 0u;
  {
    int nv = N - n0; if (nv > NPB) nv = NPB;
    const int valid = nv * 48;                 // floats; multiple of 4 (48/node)
    fx4* scratch = (fx4*)sm_wso;
    for (int idx = tid; idx < NPB*48/4; idx += 256){
      fx4 val = {0.f, 0.f, 0.f, 0.f};
      if (idx*4 < valid) val = *(const fx4*)(vec + (size_t)n0*48 + idx*4);
      scratch[idx] = val;
    }
  }
  sm_wd[tid] = wdown[tid];
  __syncthreads();

  // ---- P1: vh[ni][d][h] = sum_k vec[ni][k][d] * W_down[h][k]   (f32 math, bf16 store)
  if (tid < NPB*3){
    const int ni = tid / 3, d = tid - ni*3;
    const float* sv = (const float*)sm_wso;
    float acc[16];
    #pragma unroll
    for (int h = 0; h < 16; h++) acc[h] = 0.f;
    #pragma unroll
    for (int k = 0; k < 16; k++){
      float v = sv[ni*48 + k*3 + d];
      #pragma unroll
      for (int h = 0; h < 16; h++) acc[h] += v * sm_wd[h*16 + k];
    }
    #pragma unroll
    for (int h = 0; h < 16; h++) sm_vh[ni*48 + d*16 + h] = f2bf(acc[h]);
  }
  __syncthreads();

  // ---- P2: build merged rows [scalar | vnorm | sh | 0-pad]; load W_so/W_g/W_up/b_so/b_g
  {
    const int ni = tid >> 2;
    #pragma unroll
    for (int ii = 0; ii < 4; ii++){
      int h = (tid & 3)*4 + ii;
      float x0 = bf2f(sm_vh[ni*48 +  0 + h]);
      float x1 = bf2f(sm_vh[ni*48 + 16 + h]);
      float x2 = bf2f(sm_vh[ni*48 + 32 + h]);
      sm_merged[ni*MS + 128 + h] = f2bf(sqrtf(x0*x0 + x1*x1 + x2*x2 + 1e-8f));
    }
  }
  for (int idx = tid; idx < NPB*9; idx += 256){
    int ni = idx / 9, t = idx - ni*9;
    int g = n0 + ni;
    if (g < N){
      float cnt = sums[(size_t)g*10 + 9];
      float val = sums[(size_t)g*10 + t] / fmaxf(cnt, 1.0f);
      sm_merged[ni*MS + 144 + t] = f2bf(val);
    }
  }
  for (int idx = tid; idx < NPB*32; idx += 256){   // scalar tile: f32x4 -> bf16x4
    int ni = idx >> 5, c4 = (idx & 31) * 4;
    int g = n0 + ni;
    if (g < N){
      fx4 x = *(const fx4*)(scalar + (size_t)g*128 + c4);
      bfx4 b; b[0]=f2bf(x[0]); b[1]=f2bf(x[1]); b[2]=f2bf(x[2]); b[3]=f2bf(x[3]);
      *(bfx4*)(sm_merged + ni*MS + c4) = b;
    }
  }
  for (int idx = tid; idx < 128*153; idx += 256){
    int o = idx / 153, k = idx - o*153;
    sm_wso[o*MS + k] = f2bf(wso[idx]);
  }
  for (int idx = tid; idx < 128*15; idx += 256){
    int o = idx / 15, p = idx - o*15;
    sm_wso[o*MS + 153 + p] = 0;
  }
  for (int idx = tid; idx < 2048; idx += 256) sm_wg[idx] = f2bf(wg[idx]);
  sm_wup[tid] = wup[tid];
  if (tid < 128) sm_bso[tid] = bso[tid];
  if (tid < 16) sm_bg[tid] = bg[tid];
  __syncthreads();

  // ---- P3: s = merged @ W_so^T via MFMA 16x16x32 bf16; silu; write out0 (f32) + sact->LDS
  const int lane = tid & 63;
  const int wv   = tid >> 6;
  const int mrow = lane & 15;
  const int quad = lane >> 4;
  sfx8 afr[5];
  {
    const ushort_t* ab = sm_merged + (wv*16 + mrow)*MS + quad*8;
    #pragma unroll
    for (int ks = 0; ks < 5; ks++) afr[ks] = *(const sfx8*)(ab + ks*32);
  }
  #pragma unroll
  for (int nt = 0; nt < 8; nt++){
    fx4 acc = {0.f, 0.f, 0.f, 0.f};
    const ushort_t* bb = sm_wso + (nt*16 + mrow)*MS + quad*8;
    #pragma unroll
    for (int ks = 0; ks < 5; ks++){
      sfx8 bfr = *(const sfx8*)(bb + ks*32);
      acc = __builtin_amdgcn_mfma_f32_16x16x32_bf16(afr[ks], bfr, acc, 0, 0, 0);
    }
    const int o = nt*16 + mrow;
    const float bso_v = sm_bso[o];
    #pragma unroll
    for (int r = 0; r < 4; r++){
      int m = quad*4 + r;                       // node within wave tile
      int g = n0 + wv*16 + m;
      float s = acc[r] + bso_v;
      float sact = s / (1.f + __expf(-s));      // silu
      if (g < N) out0[(size_t)g*128 + o] = sact;
      sm_merged[(wv*16 + m)*MS + o] = f2bf(sact);  // own rows only; A-frags already in regs
    }
  }
  __syncthreads();

  // ---- P4: gate = silu(s) @ W_g^T + b_g; vrep = (vh @ W_up^T) * sigmoid(gate)
  for (int it = 0; it < 4; it++){
    int widx = tid + it*256;                    // 0..1023 -> (ni, o16)
    int ni = widx >> 4, o16 = widx & 15;
    int g = n0 + ni;
    float acc = sm_bg[o16];
    #pragma unroll
    for (int j8 = 0; j8 < 16; j8++){
      bfx8 svv = *(const bfx8*)(sm_merged + ni*MS + j8*8);
      bfx8 wv8 = *(const bfx8*)(sm_wg + o16*128 + j8*8);
      #pragma unroll
      for (int t = 0; t < 8; t++) acc += bf2f(svv[t]) * bf2f(wv8[t]);
    }
    float sig = 1.f / (1.f + __expf(-acc));
    #pragma unroll
    for (int d = 0; d < 3; d++){
      float r = 0.f;
      #pragma unroll
      for (int h = 0; h < 16; h++)
        r += bf2f(sm_vh[ni*48 + d*16 + h]) * sm_wup[o16*16 + h];
      if (g < N) out1[((size_t)g*16 + o16)*3 + d] = r * sig;
    }
  }
}

extern "C" void kernel_launch(void* const* d_in, const int* in_sizes, int n_in,
                              void* d_out, int out_size, void* d_ws, size_t ws_size,
                              hipStream_t stream)
{
  const float* scalar = (const float*)d_in[0];
  const float* vec    = (const float*)d_in[1];
  const int*   ei     = (const int*)d_in[2];
  const float* frames = (const float*)d_in[3];
  const float* wdown  = (const float*)d_in[4];
  const float* wdf    = (const float*)d_in[5];
  const float* wso    = (const float*)d_in[6];
  const float* bso    = (const float*)d_in[7];
  const float* wup    = (const float*)d_in[8];
  const float* wg     = (const float*)d_in[9];
  const float* bg     = (const float*)d_in[10];

  const int N = in_sizes[0] / 128;
  const int E = in_sizes[2] / 2;

  float* sums = (float*)d_ws;                                            // N*10 f32
  float* vdf  = (float*)((char*)d_ws + (size_t)N * 10 * sizeof(float));  // N*12 f32

  float* out0 = (float*)d_out;                    // silu(s): N x 128 f32
  float* out1 = out0 + (size_t)N * 128;           // vrep:    N x 16 x 3 f32

  (void)hipMemsetAsync(sums, 0, (size_t)N * 10 * sizeof(float), stream);
  k_vdf <<<(N + 255) / 256, 256, 0, stream>>>(vec, wdf, vdf, N);
  k_edge<<<(E + 255) / 256, 256, 0, stream>>>(ei, frames, vdf, sums, E);
  k_node<<<(N + NPB - 1) / NPB, 256, 0, stream>>>(scalar, vec, sums, wdown, wso, bso,
                                                  wup, wg, bg, out0, out1, N);
}

// Round 5
// 358.792 us; speedup vs baseline: 2.7932x; 2.7932x over previous
//
#include <hip/hip_runtime.h>

typedef unsigned short ushort_t;
typedef __attribute__((ext_vector_type(4))) unsigned short bfx4;
typedef __attribute__((ext_vector_type(8))) unsigned short bfx8;
typedef __attribute__((ext_vector_type(8))) short sfx8;
typedef __attribute__((ext_vector_type(4))) float fx4;

#define SEG  48
#define ABLK 256

__device__ __forceinline__ float bf2f(unsigned short u){
  unsigned int x = ((unsigned int)u) << 16;
  float f; __builtin_memcpy(&f, &x, 4); return f;
}
__device__ __forceinline__ unsigned short f2bf(float f){
  unsigned int x; __builtin_memcpy(&x, &f, 4);
  x += 0x7fffu + ((x >> 16) & 1u);
  return (unsigned short)(x >> 16);
}

// ---------------- Kernel A: vdf = v_pre @ W_df^T  -> (N, 12) f32 (9 + 3 pad)
__global__ void k_vdf(const float* __restrict__ vec, const float* __restrict__ wdf,
                      float* __restrict__ vdf, int N)
{
  int n = blockIdx.x * 256 + threadIdx.x;
  if (n >= N) return;
  const fx4* vp = (const fx4*)(vec + (size_t)n * 48);   // vector[n][k][d]
  float v[48];
  #pragma unroll
  for (int t = 0; t < 12; t++){
    fx4 x = vp[t];
    v[t*4+0]=x[0]; v[t*4+1]=x[1]; v[t*4+2]=x[2]; v[t*4+3]=x[3];
  }
  float out[12];
  #pragma unroll
  for (int d = 0; d < 3; d++)
    #pragma unroll
    for (int c = 0; c < 3; c++){
      float a = 0.f;
      #pragma unroll
      for (int k = 0; k < 16; k++) a += v[k*3 + d] * wdf[c*16 + k];
      out[d*3 + c] = a;                                   // vdf[n][d][c]
    }
  out[9] = out[10] = out[11] = 0.f;
  fx4* o4 = (fx4*)(vdf + (size_t)n * 12);
  o4[0] = *(fx4*)(out + 0);
  o4[1] = *(fx4*)(out + 4);
  o4[2] = *(fx4*)(out + 8);
}

// ---------------- old atomic path (ws-size fallback only)
__global__ void k_edge(const int* __restrict__ ei, const float* __restrict__ frames,
                       const float* __restrict__ vdf, float* __restrict__ sums, int E)
{
  int e = blockIdx.x * 256 + threadIdx.x;
  if (e >= E) return;
  int row = ei[e];
  const fx4* vp = (const fx4*)(vdf + (size_t)row * 12);
  fx4 a = vp[0], b = vp[1], c4 = vp[2];
  float v[9];
  v[0]=a[0]; v[1]=a[1]; v[2]=a[2]; v[3]=a[3];
  v[4]=b[0]; v[5]=b[1]; v[6]=b[2]; v[7]=b[3]; v[8]=c4[0];
  const float* fp = frames + (size_t)e * 9;
  float F[9];
  #pragma unroll
  for (int t = 0; t < 9; t++) F[t] = fp[t];
  float* sp = sums + (size_t)row * 10;
  #pragma unroll
  for (int c = 0; c < 3; c++)
    #pragma unroll
    for (int i = 0; i < 3; i++){
      float loc = F[i*3+0]*v[0+c] + F[i*3+1]*v[3+c] + F[i*3+2]*v[6+c];
      atomicAdd(&sp[c*3 + i], loc);
    }
  atomicAdd(&sp[9], 1.0f);
}

// ---------------- Phase A: bin edge ids by row>>7, per-(ablock,bin) segments, no global atomics
__global__ __launch_bounds__(256) void k_binA(const int* __restrict__ ei,
                                              const float* __restrict__ frames,
                                              const float* __restrict__ vdf,
                                              int* __restrict__ counts, int* __restrict__ ids,
                                              float* __restrict__ sums, int E, int NB, int EPB)
{
  __shared__ int smc[512];                  // NB <= 512 bin counters
  const int ablk = blockIdx.x, tid = threadIdx.x;
  for (int b = tid; b < NB; b += 256) smc[b] = 0;
  __syncthreads();
  const int e0 = ablk * EPB;
  for (int i = tid; i < EPB; i += 256){
    int e = e0 + i;
    if (e < E){
      int row = ei[e];
      int bin = row >> 7;
      int r = atomicAdd(&smc[bin], 1);      // ds_add_rtn_u32: rank within (ablk,bin)
      if (r < SEG){
        ids[((size_t)ablk * NB + bin) * SEG + r] = e;
      } else {
        // overflow fallback (prob ~1e-8): direct device atomics, correctness-preserving
        const fx4* vp = (const fx4*)(vdf + (size_t)row * 12);
        fx4 a = vp[0], b4 = vp[1], c4 = vp[2];
        float v[9];
        v[0]=a[0]; v[1]=a[1]; v[2]=a[2]; v[3]=a[3];
        v[4]=b4[0]; v[5]=b4[1]; v[6]=b4[2]; v[7]=b4[3]; v[8]=c4[0];
        const float* fp = frames + (size_t)e * 9;
        float* sp = sums + (size_t)row * 10;
        #pragma unroll
        for (int c = 0; c < 3; c++)
          #pragma unroll
          for (int ii = 0; ii < 3; ii++){
            float loc = fp[ii*3+0]*v[0+c] + fp[ii*3+1]*v[3+c] + fp[ii*3+2]*v[6+c];
            atomicAdd(&sp[c*3 + ii], loc);
          }
        atomicAdd(&sp[9], 1.0f);
      }
    }
  }
  __syncthreads();
  for (int b = tid; b < NB; b += 256)
    counts[(size_t)b * ABLK + ablk] = min(smc[b], SEG);   // transposed: coalesced in phase B
}

// ---------------- Phase B: one block per bin; LDS accumulate (ds_add_f32), plain store
__global__ __launch_bounds__(256) void k_binB(const int* __restrict__ ei,
                                              const float* __restrict__ frames,
                                              const float* __restrict__ vdf,
                                              const int* __restrict__ counts,
                                              const int* __restrict__ ids,
                                              float* __restrict__ sums, int N, int NB)
{
  __shared__ int   s_pref[ABLK + 1];
  __shared__ float s_acc[128 * 11];         // stride 11: gcd(11,32)=1 -> spread banks
  const int bin = blockIdx.x, tid = threadIdx.x;

  int c = counts[(size_t)bin * ABLK + tid];
  s_pref[tid + 1] = c;
  if (tid == 0) s_pref[0] = 0;
  for (int i = tid; i < 128*11; i += 256) s_acc[i] = 0.f;
  __syncthreads();
  // Hillis-Steele inclusive scan over s_pref[1..256]
  #pragma unroll
  for (int off = 1; off < ABLK; off <<= 1){
    int v = (tid + 1 > off) ? s_pref[tid + 1 - off] : 0;
    __syncthreads();
    s_pref[tid + 1] += v;
    __syncthreads();
  }
  const int total = s_pref[ABLK];

  for (int base = 0; base < total; base += 256){
    int idx = base + tid;
    if (idx < total){
      int lo = 0, hi = ABLK;                 // find ablk: pref[ablk] <= idx < pref[ablk+1]
      while (hi - lo > 1){ int mid = (lo + hi) >> 1; if (s_pref[mid] <= idx) lo = mid; else hi = mid; }
      int slot = idx - s_pref[lo];
      int e   = ids[((size_t)lo * NB + bin) * SEG + slot];
      int row = ei[e];
      const float* fp = frames + (size_t)e * 9;
      float F[9];
      #pragma unroll
      for (int t = 0; t < 9; t++) F[t] = fp[t];
      const fx4* vp = (const fx4*)(vdf + (size_t)row * 12);
      fx4 a = vp[0], b4 = vp[1], c4 = vp[2];
      float v[9];
      v[0]=a[0]; v[1]=a[1]; v[2]=a[2]; v[3]=a[3];
      v[4]=b4[0]; v[5]=b4[1]; v[6]=b4[2]; v[7]=b4[3]; v[8]=c4[0];
      float* ap = s_acc + (row & 127) * 11;
      #pragma unroll
      for (int cc = 0; cc < 3; cc++)
        #pragma unroll
        for (int ii = 0; ii < 3; ii++){
          float loc = F[ii*3+0]*v[0+cc] + F[ii*3+1]*v[3+cc] + F[ii*3+2]*v[6+cc];
          atomicAdd(&ap[cc*3 + ii], loc);    // ds_add_f32 (no rtn)
        }
      atomicAdd(&ap[9], 1.0f);
    }
  }
  __syncthreads();
  const int base_node = bin << 7;
  const int nn = min(128, N - base_node);
  for (int t = tid; t < nn * 10; t += 256){
    int ni = t / 10, sl = t - ni * 10;
    size_t gi = (size_t)(base_node + ni) * 10 + sl;
    sums[gi] = sums[gi] + s_acc[ni * 11 + sl];  // exclusive ownership; base holds rare fallback adds
  }
}

// ---------------- Kernel C: node main pass (vh, vnorm, merged, MFMA s, silu, gate, vrep)
#define NPB 64
#define MS  168   // padded row stride (elements); 168*2B/4 = 84 ≡ 20 mod 32 -> <=2-way LDS conflicts

__global__ __launch_bounds__(256) void k_node(
    const float* __restrict__ scalar, const float* __restrict__ vec,
    const float* __restrict__ sums,
    const float* __restrict__ wdown, const float* __restrict__ wso,
    const float* __restrict__ bso,   const float* __restrict__ wup,
    const float* __restrict__ wg,    const float* __restrict__ bg,
    float* __restrict__ out0, float* __restrict__ out1, int N)
{
  __shared__ __align__(16) ushort_t sm_merged[NPB * MS];
  __shared__ __align__(16) ushort_t sm_wso[128 * MS];
  __shared__ __align__(16) ushort_t sm_vh[NPB * 48];
  __shared__ __align__(16) ushort_t sm_wg[16 * 128];
  __shared__ float  sm_wup[256];
  __shared__ float  sm_wd[256];
  __shared__ float  sm_bso[128];
  __shared__ float  sm_bg[16];

  const int tid = threadIdx.x;
  const int n0  = blockIdx.x * NPB;

  for (int i = tid; i < NPB*MS/2; i += 256) ((unsigned int*)sm_merged)[i] = 0u;
  {
    int nv = N - n0; if (nv > NPB) nv = NPB;
    const int valid = nv * 48;
    fx4* scratch = (fx4*)sm_wso;
    for (int idx = tid; idx < NPB*48/4; idx += 256){
      fx4 val = {0.f, 0.f, 0.f, 0.f};
      if (idx*4 < valid) val = *(const fx4*)(vec + (size_t)n0*48 + idx*4);
      scratch[idx] = val;
    }
  }
  sm_wd[tid] = wdown[tid];
  __syncthreads();

  if (tid < NPB*3){
    const int ni = tid / 3, d = tid - ni*3;
    const float* sv = (const float*)sm_wso;
    float acc[16];
    #pragma unroll
    for (int h = 0; h < 16; h++) acc[h] = 0.f;
    #pragma unroll
    for (int k = 0; k < 16; k++){
      float v = sv[ni*48 + k*3 + d];
      #pragma unroll
      for (int h = 0; h < 16; h++) acc[h] += v * sm_wd[h*16 + k];
    }
    #pragma unroll
    for (int h = 0; h < 16; h++) sm_vh[ni*48 + d*16 + h] = f2bf(acc[h]);
  }
  __syncthreads();

  {
    const int ni = tid >> 2;
    #pragma unroll
    for (int ii = 0; ii < 4; ii++){
      int h = (tid & 3)*4 + ii;
      float x0 = bf2f(sm_vh[ni*48 +  0 + h]);
      float x1 = bf2f(sm_vh[ni*48 + 16 + h]);
      float x2 = bf2f(sm_vh[ni*48 + 32 + h]);
      sm_merged[ni*MS + 128 + h] = f2bf(sqrtf(x0*x0 + x1*x1 + x2*x2 + 1e-8f));
    }
  }
  for (int idx = tid; idx < NPB*9; idx += 256){
    int ni = idx / 9, t = idx - ni*9;
    int g = n0 + ni;
    if (g < N){
      float cnt = sums[(size_t)g*10 + 9];
      float val = sums[(size_t)g*10 + t] / fmaxf(cnt, 1.0f);
      sm_merged[ni*MS + 144 + t] = f2bf(val);
    }
  }
  for (int idx = tid; idx < NPB*32; idx += 256){
    int ni = idx >> 5, c4 = (idx & 31) * 4;
    int g = n0 + ni;
    if (g < N){
      fx4 x = *(const fx4*)(scalar + (size_t)g*128 + c4);
      bfx4 b; b[0]=f2bf(x[0]); b[1]=f2bf(x[1]); b[2]=f2bf(x[2]); b[3]=f2bf(x[3]);
      *(bfx4*)(sm_merged + ni*MS + c4) = b;
    }
  }
  for (int idx = tid; idx < 128*153; idx += 256){
    int o = idx / 153, k = idx - o*153;
    sm_wso[o*MS + k] = f2bf(wso[idx]);
  }
  for (int idx = tid; idx < 128*15; idx += 256){
    int o = idx / 15, p = idx - o*15;
    sm_wso[o*MS + 153 + p] = 0;
  }
  for (int idx = tid; idx < 2048; idx += 256) sm_wg[idx] = f2bf(wg[idx]);
  sm_wup[tid] = wup[tid];
  if (tid < 128) sm_bso[tid] = bso[tid];
  if (tid < 16) sm_bg[tid] = bg[tid];
  __syncthreads();

  const int lane = tid & 63;
  const int wv   = tid >> 6;
  const int mrow = lane & 15;
  const int quad = lane >> 4;
  sfx8 afr[5];
  {
    const ushort_t* ab = sm_merged + (wv*16 + mrow)*MS + quad*8;
    #pragma unroll
    for (int ks = 0; ks < 5; ks++) afr[ks] = *(const sfx8*)(ab + ks*32);
  }
  #pragma unroll
  for (int nt = 0; nt < 8; nt++){
    fx4 acc = {0.f, 0.f, 0.f, 0.f};
    const ushort_t* bb = sm_wso + (nt*16 + mrow)*MS + quad*8;
    #pragma unroll
    for (int ks = 0; ks < 5; ks++){
      sfx8 bfr = *(const sfx8*)(bb + ks*32);
      acc = __builtin_amdgcn_mfma_f32_16x16x32_bf16(afr[ks], bfr, acc, 0, 0, 0);
    }
    const int o = nt*16 + mrow;
    const float bso_v = sm_bso[o];
    #pragma unroll
    for (int r = 0; r < 4; r++){
      int m = quad*4 + r;
      int g = n0 + wv*16 + m;
      float s = acc[r] + bso_v;
      float sact = s / (1.f + __expf(-s));
      if (g < N) out0[(size_t)g*128 + o] = sact;
      sm_merged[(wv*16 + m)*MS + o] = f2bf(sact);
    }
  }
  __syncthreads();

  for (int it = 0; it < 4; it++){
    int widx = tid + it*256;
    int ni = widx >> 4, o16 = widx & 15;
    int g = n0 + ni;
    float acc = sm_bg[o16];
    #pragma unroll
    for (int j8 = 0; j8 < 16; j8++){
      bfx8 svv = *(const bfx8*)(sm_merged + ni*MS + j8*8);
      bfx8 wv8 = *(const bfx8*)(sm_wg + o16*128 + j8*8);
      #pragma unroll
      for (int t = 0; t < 8; t++) acc += bf2f(svv[t]) * bf2f(wv8[t]);
    }
    float sig = 1.f / (1.f + __expf(-acc));
    #pragma unroll
    for (int d = 0; d < 3; d++){
      float r = 0.f;
      #pragma unroll
      for (int h = 0; h < 16; h++)
        r += bf2f(sm_vh[ni*48 + d*16 + h]) * sm_wup[o16*16 + h];
      if (g < N) out1[((size_t)g*16 + o16)*3 + d] = r * sig;
    }
  }
}

extern "C" void kernel_launch(void* const* d_in, const int* in_sizes, int n_in,
                              void* d_out, int out_size, void* d_ws, size_t ws_size,
                              hipStream_t stream)
{
  const float* scalar = (const float*)d_in[0];
  const float* vec    = (const float*)d_in[1];
  const int*   ei     = (const int*)d_in[2];
  const float* frames = (const float*)d_in[3];
  const float* wdown  = (const float*)d_in[4];
  const float* wdf    = (const float*)d_in[5];
  const float* wso    = (const float*)d_in[6];
  const float* bso    = (const float*)d_in[7];
  const float* wup    = (const float*)d_in[8];
  const float* wg     = (const float*)d_in[9];
  const float* bg     = (const float*)d_in[10];

  const int N = in_sizes[0] / 128;
  const int E = in_sizes[2] / 2;
  const int NB  = (N + 127) >> 7;                 // 391 bins of 128 nodes
  const int EPB = (E + ABLK - 1) / ABLK;          // 6250 edges per phase-A block

  char* wp = (char*)d_ws;
  float* sums  = (float*)wp;                       wp += (size_t)N * 10 * sizeof(float);
  float* vdf   = (float*)wp;                       wp += (size_t)N * 12 * sizeof(float);
  int*   counts= (int*)wp;                         wp += (size_t)NB * ABLK * sizeof(int);
  int*   ids   = (int*)wp;                         wp += (size_t)ABLK * NB * SEG * sizeof(int);
  const size_t ws_needed = (size_t)(wp - (char*)d_ws);

  float* out0 = (float*)d_out;                    // silu(s): N x 128 f32
  float* out1 = out0 + (size_t)N * 128;           // vrep:    N x 16 x 3 f32

  (void)hipMemsetAsync(sums, 0, (size_t)N * 10 * sizeof(float), stream);
  k_vdf<<<(N + 255) / 256, 256, 0, stream>>>(vec, wdf, vdf, N);
  if (ws_size >= ws_needed && NB <= 512){
    k_binA<<<ABLK, 256, 0, stream>>>(ei, frames, vdf, counts, ids, sums, E, NB, EPB);
    k_binB<<<NB, 256, 0, stream>>>(ei, frames, vdf, counts, ids, sums, N, NB);
  } else {
    k_edge<<<(E + 255) / 256, 256, 0, stream>>>(ei, frames, vdf, sums, E);
  }
  k_node<<<(N + NPB - 1) / NPB, 256, 0, stream>>>(scalar, vec, sums, wdown, wso, bso,
                                                  wup, wg, bg, out0, out1, N);
}

// Round 6
// 322.731 us; speedup vs baseline: 3.1053x; 1.1117x over previous
//
#include <hip/hip_runtime.h>

typedef unsigned short ushort_t;
typedef __attribute__((ext_vector_type(4))) unsigned short bfx4;
typedef __attribute__((ext_vector_type(8))) unsigned short bfx8;
typedef __attribute__((ext_vector_type(8))) short sfx8;
typedef __attribute__((ext_vector_type(4))) float fx4;

#define SEG   48
#define ABLK  256
#define SPLIT 8
#define APS   (ABLK / SPLIT)   // 32 phase-A segments per phase-B sub-block

__device__ __forceinline__ float bf2f(unsigned short u){
  unsigned int x = ((unsigned int)u) << 16;
  float f; __builtin_memcpy(&f, &x, 4); return f;
}
__device__ __forceinline__ unsigned short f2bf(float f){
  unsigned int x; __builtin_memcpy(&x, &f, 4);
  x += 0x7fffu + ((x >> 16) & 1u);
  return (unsigned short)(x >> 16);
}

// ---------------- Kernel A: vdf = v_pre @ W_df^T  -> (N, 12) f32 (9 + 3 pad)
__global__ void k_vdf(const float* __restrict__ vec, const float* __restrict__ wdf,
                      float* __restrict__ vdf, int N)
{
  int n = blockIdx.x * 256 + threadIdx.x;
  if (n >= N) return;
  const fx4* vp = (const fx4*)(vec + (size_t)n * 48);   // vector[n][k][d]
  float v[48];
  #pragma unroll
  for (int t = 0; t < 12; t++){
    fx4 x = vp[t];
    v[t*4+0]=x[0]; v[t*4+1]=x[1]; v[t*4+2]=x[2]; v[t*4+3]=x[3];
  }
  float out[12];
  #pragma unroll
  for (int d = 0; d < 3; d++)
    #pragma unroll
    for (int c = 0; c < 3; c++){
      float a = 0.f;
      #pragma unroll
      for (int k = 0; k < 16; k++) a += v[k*3 + d] * wdf[c*16 + k];
      out[d*3 + c] = a;                                   // vdf[n][d][c]
    }
  out[9] = out[10] = out[11] = 0.f;
  fx4* o4 = (fx4*)(vdf + (size_t)n * 12);
  o4[0] = *(fx4*)(out + 0);
  o4[1] = *(fx4*)(out + 4);
  o4[2] = *(fx4*)(out + 8);
}

// ---------------- old atomic path (ws-size fallback only)
__global__ void k_edge(const int* __restrict__ ei, const float* __restrict__ frames,
                       const float* __restrict__ vdf, float* __restrict__ sums, int E)
{
  int e = blockIdx.x * 256 + threadIdx.x;
  if (e >= E) return;
  int row = ei[e];
  const fx4* vp = (const fx4*)(vdf + (size_t)row * 12);
  fx4 a = vp[0], b = vp[1], c4 = vp[2];
  float v[9];
  v[0]=a[0]; v[1]=a[1]; v[2]=a[2]; v[3]=a[3];
  v[4]=b[0]; v[5]=b[1]; v[6]=b[2]; v[7]=b[3]; v[8]=c4[0];
  const float* fp = frames + (size_t)e * 9;
  float F[9];
  #pragma unroll
  for (int t = 0; t < 9; t++) F[t] = fp[t];
  float* sp = sums + (size_t)row * 10;
  #pragma unroll
  for (int c = 0; c < 3; c++)
    #pragma unroll
    for (int i = 0; i < 3; i++){
      float loc = F[i*3+0]*v[0+c] + F[i*3+1]*v[3+c] + F[i*3+2]*v[6+c];
      atomicAdd(&sp[c*3 + i], loc);
    }
  atomicAdd(&sp[9], 1.0f);
}

// ---------------- Phase A: bin packed (e<<7 | row&127) by row>>7 into per-(ablock,bin) segments
__global__ __launch_bounds__(256) void k_binA(const int* __restrict__ ei,
                                              const float* __restrict__ frames,
                                              const float* __restrict__ vdf,
                                              int* __restrict__ counts, int* __restrict__ ids,
                                              float* __restrict__ sums, int E, int NB, int EPB)
{
  __shared__ int smc[512];                  // NB <= 512 bin counters
  const int ablk = blockIdx.x, tid = threadIdx.x;
  for (int b = tid; b < NB; b += 256) smc[b] = 0;
  __syncthreads();
  const int e0 = ablk * EPB;
  for (int i = tid; i < EPB; i += 256){
    int e = e0 + i;
    if (e < E){
      int row = ei[e];
      int bin = row >> 7;
      int r = atomicAdd(&smc[bin], 1);      // ds_add_rtn_u32: rank within (ablk,bin)
      if (r < SEG){
        ids[((size_t)ablk * NB + bin) * SEG + r] = (e << 7) | (row & 127);
      } else {
        // overflow fallback (prob ~1e-8): direct device atomics, correctness-preserving
        const fx4* vp = (const fx4*)(vdf + (size_t)row * 12);
        fx4 a = vp[0], b4 = vp[1], c4 = vp[2];
        float v[9];
        v[0]=a[0]; v[1]=a[1]; v[2]=a[2]; v[3]=a[3];
        v[4]=b4[0]; v[5]=b4[1]; v[6]=b4[2]; v[7]=b4[3]; v[8]=c4[0];
        const float* fp = frames + (size_t)e * 9;
        float* sp = sums + (size_t)row * 10;
        #pragma unroll
        for (int c = 0; c < 3; c++)
          #pragma unroll
          for (int ii = 0; ii < 3; ii++){
            float loc = fp[ii*3+0]*v[0+c] + fp[ii*3+1]*v[3+c] + fp[ii*3+2]*v[6+c];
            atomicAdd(&sp[c*3 + ii], loc);
          }
        atomicAdd(&sp[9], 1.0f);
      }
    }
  }
  __syncthreads();
  for (int b = tid; b < NB; b += 256)
    counts[(size_t)b * ABLK + ablk] = min(smc[b], SEG);   // transposed: coalesced in phase B
}

// ---------------- Phase B: (bin, sp) sub-blocks; LDS accumulate; write partial tables
__global__ __launch_bounds__(256) void k_binB(const float* __restrict__ frames,
                                              const float* __restrict__ vdf,
                                              const int* __restrict__ counts,
                                              const int* __restrict__ ids,
                                              float* __restrict__ part, int N, int NB)
{
  __shared__ int   s_pref[APS + 1];
  __shared__ float s_acc[128 * 11];         // stride 11: gcd(11,32)=1 -> spread banks
  __shared__ float s_vdf[128 * 12];         // this bin's vdf rows
  const int bin = blockIdx.x >> 3, sp = blockIdx.x & (SPLIT - 1), tid = threadIdx.x;

  if (tid < APS) s_pref[tid + 1] = counts[(size_t)bin * ABLK + sp * APS + tid];
  if (tid == 0) s_pref[0] = 0;
  for (int i = tid; i < 128*11; i += 256) s_acc[i] = 0.f;
  for (int i = tid; i < 128*12; i += 256){
    int node = (bin << 7) + (i / 12);
    s_vdf[i] = (node < N) ? vdf[(size_t)(bin << 7) * 12 + i] : 0.f;
  }
  __syncthreads();
  #pragma unroll
  for (int off = 1; off < APS; off <<= 1){
    int v = 0;
    if (tid < APS && tid + 1 > off) v = s_pref[tid + 1 - off];
    __syncthreads();
    if (tid < APS) s_pref[tid + 1] += v;
    __syncthreads();
  }
  const int total = s_pref[APS];

  for (int base = 0; base < total; base += 256){
    int idx = base + tid;
    if (idx < total){
      int lo = 0, hi = APS;                  // find seg: pref[seg] <= idx < pref[seg+1]
      while (hi - lo > 1){ int mid = (lo + hi) >> 1; if (s_pref[mid] <= idx) lo = mid; else hi = mid; }
      int slot = idx - s_pref[lo];
      int ablk = sp * APS + lo;
      int packed = ids[((size_t)ablk * NB + bin) * SEG + slot];
      int row7 = packed & 127;
      int e    = ((unsigned int)packed) >> 7;
      const float* fp = frames + (size_t)e * 9;
      float F[9];
      #pragma unroll
      for (int t = 0; t < 9; t++) F[t] = fp[t];
      const float* v = s_vdf + row7 * 12;    // v[j*3+c]
      float* ap = s_acc + row7 * 11;
      #pragma unroll
      for (int cc = 0; cc < 3; cc++)
        #pragma unroll
        for (int ii = 0; ii < 3; ii++){
          float loc = F[ii*3+0]*v[0+cc] + F[ii*3+1]*v[3+cc] + F[ii*3+2]*v[6+cc];
          atomicAdd(&ap[cc*3 + ii], loc);    // ds_add_f32 (no rtn)
        }
      atomicAdd(&ap[9], 1.0f);
    }
  }
  __syncthreads();
  float* pb = part + ((size_t)bin * SPLIT + sp) * 1280;
  for (int i = tid; i < 1280; i += 256)
    pb[i] = s_acc[(i / 10) * 11 + (i % 10)];
}

// ---------------- Kernel C: node main pass (vh, vnorm, merged, MFMA s, silu, gate, vrep)
#define NPB 64
#define MS  168   // padded row stride (elements); 168*2B/4 = 84 ≡ 20 mod 32 -> <=2-way LDS conflicts

__global__ __launch_bounds__(256) void k_node(
    const float* __restrict__ scalar, const float* __restrict__ vec,
    const float* __restrict__ sums,   const float* __restrict__ part,
    const float* __restrict__ wdown, const float* __restrict__ wso,
    const float* __restrict__ bso,   const float* __restrict__ wup,
    const float* __restrict__ wg,    const float* __restrict__ bg,
    float* __restrict__ out0, float* __restrict__ out1, int N)
{
  __shared__ __align__(16) ushort_t sm_merged[NPB * MS];
  __shared__ __align__(16) ushort_t sm_wso[128 * MS];
  __shared__ __align__(16) ushort_t sm_vh[NPB * 48];
  __shared__ __align__(16) ushort_t sm_wg[16 * 128];
  __shared__ float  sm_sh[NPB * 10];
  __shared__ float  sm_wup[256];
  __shared__ float  sm_wd[256];
  __shared__ float  sm_bso[128];
  __shared__ float  sm_bg[16];

  const int tid = threadIdx.x;
  const int n0  = blockIdx.x * NPB;

  for (int i = tid; i < NPB*MS/2; i += 256) ((unsigned int*)sm_merged)[i] = 0u;
  {
    int nv = N - n0; if (nv > NPB) nv = NPB;
    const int valid = nv * 48;
    fx4* scratch = (fx4*)sm_wso;
    for (int idx = tid; idx < NPB*48/4; idx += 256){
      fx4 val = {0.f, 0.f, 0.f, 0.f};
      if (idx*4 < valid) val = *(const fx4*)(vec + (size_t)n0*48 + idx*4);
      scratch[idx] = val;
    }
  }
  sm_wd[tid] = wdown[tid];
  __syncthreads();

  // P1a: vh (threads 0..191)
  if (tid < NPB*3){
    const int ni = tid / 3, d = tid - ni*3;
    const float* sv = (const float*)sm_wso;
    float acc[16];
    #pragma unroll
    for (int h = 0; h < 16; h++) acc[h] = 0.f;
    #pragma unroll
    for (int k = 0; k < 16; k++){
      float v = sv[ni*48 + k*3 + d];
      #pragma unroll
      for (int h = 0; h < 16; h++) acc[h] += v * sm_wd[h*16 + k];
    }
    #pragma unroll
    for (int h = 0; h < 16; h++) sm_vh[ni*48 + d*16 + h] = f2bf(acc[h]);
  }
  // P1b: aggregate scatter partials (all threads; no sync needed vs P1a)
  for (int idx = tid; idx < NPB*10; idx += 256){
    int ni = idx / 10, sl = idx - ni*10;
    int g = n0 + ni;
    float acc = 0.f;
    if (g < N){
      acc = sums[(size_t)g*10 + sl];           // rare overflow-fallback adds (usually 0)
      if (part){
        const float* pb = part + ((size_t)(g >> 7) * SPLIT) * 1280 + (g & 127) * 10 + sl;
        #pragma unroll
        for (int sp = 0; sp < SPLIT; sp++) acc += pb[(size_t)sp * 1280];
      }
    }
    sm_sh[idx] = acc;
  }
  __syncthreads();

  {
    const int ni = tid >> 2;
    #pragma unroll
    for (int ii = 0; ii < 4; ii++){
      int h = (tid & 3)*4 + ii;
      float x0 = bf2f(sm_vh[ni*48 +  0 + h]);
      float x1 = bf2f(sm_vh[ni*48 + 16 + h]);
      float x2 = bf2f(sm_vh[ni*48 + 32 + h]);
      sm_merged[ni*MS + 128 + h] = f2bf(sqrtf(x0*x0 + x1*x1 + x2*x2 + 1e-8f));
    }
  }
  for (int idx = tid; idx < NPB*9; idx += 256){
    int ni = idx / 9, t = idx - ni*9;
    float cnt = sm_sh[ni*10 + 9];
    sm_merged[ni*MS + 144 + t] = f2bf(sm_sh[ni*10 + t] / fmaxf(cnt, 1.0f));
  }
  for (int idx = tid; idx < NPB*32; idx += 256){
    int ni = idx >> 5, c4 = (idx & 31) * 4;
    int g = n0 + ni;
    if (g < N){
      fx4 x = *(const fx4*)(scalar + (size_t)g*128 + c4);
      bfx4 b; b[0]=f2bf(x[0]); b[1]=f2bf(x[1]); b[2]=f2bf(x[2]); b[3]=f2bf(x[3]);
      *(bfx4*)(sm_merged + ni*MS + c4) = b;
    }
  }
  for (int idx = tid; idx < 128*153; idx += 256){
    int o = idx / 153, k = idx - o*153;
    sm_wso[o*MS + k] = f2bf(wso[idx]);
  }
  for (int idx = tid; idx < 128*15; idx += 256){
    int o = idx / 15, p = idx - o*15;
    sm_wso[o*MS + 153 + p] = 0;
  }
  for (int idx = tid; idx < 2048; idx += 256) sm_wg[idx] = f2bf(wg[idx]);
  sm_wup[tid] = wup[tid];
  if (tid < 128) sm_bso[tid] = bso[tid];
  if (tid < 16) sm_bg[tid] = bg[tid];
  __syncthreads();

  const int lane = tid & 63;
  const int wv   = tid >> 6;
  const int mrow = lane & 15;
  const int quad = lane >> 4;
  sfx8 afr[5];
  {
    const ushort_t* ab = sm_merged + (wv*16 + mrow)*MS + quad*8;
    #pragma unroll
    for (int ks = 0; ks < 5; ks++) afr[ks] = *(const sfx8*)(ab + ks*32);
  }
  #pragma unroll
  for (int nt = 0; nt < 8; nt++){
    fx4 acc = {0.f, 0.f, 0.f, 0.f};
    const ushort_t* bb = sm_wso + (nt*16 + mrow)*MS + quad*8;
    #pragma unroll
    for (int ks = 0; ks < 5; ks++){
      sfx8 bfr = *(const sfx8*)(bb + ks*32);
      acc = __builtin_amdgcn_mfma_f32_16x16x32_bf16(afr[ks], bfr, acc, 0, 0, 0);
    }
    const int o = nt*16 + mrow;
    const float bso_v = sm_bso[o];
    #pragma unroll
    for (int r = 0; r < 4; r++){
      int m = quad*4 + r;
      int g = n0 + wv*16 + m;
      float s = acc[r] + bso_v;
      float sact = s / (1.f + __expf(-s));
      if (g < N) out0[(size_t)g*128 + o] = sact;
      sm_merged[(wv*16 + m)*MS + o] = f2bf(sact);
    }
  }
  __syncthreads();

  for (int it = 0; it < 4; it++){
    int widx = tid + it*256;
    int ni = widx >> 4, o16 = widx & 15;
    int g = n0 + ni;
    float acc = sm_bg[o16];
    #pragma unroll
    for (int j8 = 0; j8 < 16; j8++){
      bfx8 svv = *(const bfx8*)(sm_merged + ni*MS + j8*8);
      bfx8 wv8 = *(const bfx8*)(sm_wg + o16*128 + j8*8);
      #pragma unroll
      for (int t = 0; t < 8; t++) acc += bf2f(svv[t]) * bf2f(wv8[t]);
    }
    float sig = 1.f / (1.f + __expf(-acc));
    #pragma unroll
    for (int d = 0; d < 3; d++){
      float r = 0.f;
      #pragma unroll
      for (int h = 0; h < 16; h++)
        r += bf2f(sm_vh[ni*48 + d*16 + h]) * sm_wup[o16*16 + h];
      if (g < N) out1[((size_t)g*16 + o16)*3 + d] = r * sig;
    }
  }
}

extern "C" void kernel_launch(void* const* d_in, const int* in_sizes, int n_in,
                              void* d_out, int out_size, void* d_ws, size_t ws_size,
                              hipStream_t stream)
{
  const float* scalar = (const float*)d_in[0];
  const float* vec    = (const float*)d_in[1];
  const int*   ei     = (const int*)d_in[2];
  const float* frames = (const float*)d_in[3];
  const float* wdown  = (const float*)d_in[4];
  const float* wdf    = (const float*)d_in[5];
  const float* wso    = (const float*)d_in[6];
  const float* bso    = (const float*)d_in[7];
  const float* wup    = (const float*)d_in[8];
  const float* wg     = (const float*)d_in[9];
  const float* bg     = (const float*)d_in[10];

  const int N = in_sizes[0] / 128;
  const int E = in_sizes[2] / 2;
  const int NB  = (N + 127) >> 7;                 // 391 bins of 128 nodes
  const int EPB = (E + ABLK - 1) / ABLK;          // edges per phase-A block

  char* wp = (char*)d_ws;
  float* sums  = (float*)wp;                       wp += (size_t)N * 10 * sizeof(float);
  float* vdf   = (float*)wp;                       wp += (size_t)N * 12 * sizeof(float);
  int*   counts= (int*)wp;                         wp += (size_t)NB * ABLK * sizeof(int);
  int*   ids   = (int*)wp;                         wp += (size_t)ABLK * NB * SEG * sizeof(int);
  float* part  = (float*)wp;                       wp += (size_t)NB * SPLIT * 1280 * sizeof(float);
  const size_t ws_needed = (size_t)(wp - (char*)d_ws);

  float* out0 = (float*)d_out;                    // silu(s): N x 128 f32
  float* out1 = out0 + (size_t)N * 128;           // vrep:    N x 16 x 3 f32

  const bool binned = (ws_size >= ws_needed) && (NB <= 512) && (E < (1 << 25));

  (void)hipMemsetAsync(sums, 0, (size_t)N * 10 * sizeof(float), stream);
  k_vdf<<<(N + 255) / 256, 256, 0, stream>>>(vec, wdf, vdf, N);
  if (binned){
    k_binA<<<ABLK, 256, 0, stream>>>(ei, frames, vdf, counts, ids, sums, E, NB, EPB);
    k_binB<<<NB * SPLIT, 256, 0, stream>>>(frames, vdf, counts, ids, part, N, NB);
  } else {
    k_edge<<<(E + 255) / 256, 256, 0, stream>>>(ei, frames, vdf, sums, E);
  }
  k_node<<<(N + NPB - 1) / NPB, 256, 0, stream>>>(scalar, vec, sums, binned ? part : nullptr,
                                                  wdown, wso, bso, wup, wg, bg, out0, out1, N);
}